// Round 1
// 493.409 us; speedup vs baseline: 1.0620x; 1.0620x over previous
//
#include <hip/hip_runtime.h>
#include <hip/hip_fp16.h>

#define F_IN 512
#define HID  16
#define NCLS 7
#define BSH  8            // log2(nodes per bucket)
#define NPB  256          // nodes per bucket
#define MAXBKT 1024       // supports n <= 262144
#define GRID_P 512        // blocks for hist/partition passes

// ---------------- GEMM1 body (used by fused kernels) ----------------
// h1 = fp32(x @ W1) stored fp16, 32B rows (3.2MB -> per-XCD-L2-resident for gathers).
__device__ __forceinline__ void gemm1_block(const float* __restrict__ x,
                                            const float* __restrict__ W1,
                                            __half* __restrict__ h1, int n,
                                            int vblk, int tid) {
    int node = vblk * 256 + tid;
    if (node >= n) return;
    float acc[HID];
#pragma unroll
    for (int j = 0; j < HID; j++) acc[j] = 0.f;
    const float* xr = x + (size_t)node * F_IN;
    for (int k0 = 0; k0 < F_IN; k0 += 32) {
        float4 xv[8];
        const float4* xp = (const float4*)(xr + k0);
#pragma unroll
        for (int u = 0; u < 8; u++) xv[u] = xp[u];
#pragma unroll
        for (int u = 0; u < 8; u++) {
#pragma unroll
            for (int kk = 0; kk < 4; kk++) {
                float xk = ((const float*)&xv[u])[kk];
                const float* wr = W1 + (size_t)(k0 + u * 4 + kk) * HID;
#pragma unroll
                for (int j = 0; j < HID; j++) acc[j] = fmaf(xk, wr[j], acc[j]);
            }
        }
    }
    __half2 hp[8];
#pragma unroll
    for (int j = 0; j < 8; j++)
        hp[j] = __float22half2_rn(float2{acc[2 * j], acc[2 * j + 1]});
    float4* o4 = (float4*)(h1 + (size_t)node * HID);
    o4[0] = *(float4*)&hp[0];
    o4[1] = *(float4*)&hp[4];
}

// ---------------- bucketed CSR build ----------------

__global__ void k_zero(int* __restrict__ p, int m) {
    int i = blockIdx.x * blockDim.x + threadIdx.x;
    if (i < m) p[i] = 0;
}

// bhist (blocks [0,GRID_P)) || gemm1 chunk A (blocks >= GRID_P)
__global__ __launch_bounds__(256) void k_bhist_gemm(
    const int* __restrict__ dst, int* __restrict__ bcnt, int E, int nbkt, int chunk,
    const float* __restrict__ x, const float* __restrict__ W1,
    __half* __restrict__ h1, int n) {
    __shared__ int h[MAXBKT];
    if (blockIdx.x >= GRID_P) {
        gemm1_block(x, W1, h1, n, (int)blockIdx.x - GRID_P, threadIdx.x);
        return;
    }
    for (int i = threadIdx.x; i < nbkt; i += blockDim.x) h[i] = 0;
    __syncthreads();
    int base = blockIdx.x * chunk;
    int end = min(base + chunk, E);
    for (int e = base + threadIdx.x; e < end; e += blockDim.x)
        atomicAdd(&h[((unsigned)dst[e]) >> BSH], 1);
    __syncthreads();
    for (int i = threadIdx.x; i < nbkt; i += blockDim.x)
        if (h[i]) atomicAdd(&bcnt[i * 16], h[i]);   // stride-16: one counter per line
}

__global__ void k_bscan(const int* __restrict__ bcnt, int* __restrict__ bptr,
                        int* __restrict__ bcur, int nbkt) {
    __shared__ int s[1024];
    int tid = threadIdx.x;
    int v = (tid < nbkt) ? bcnt[tid * 16] : 0;
    s[tid] = v;
    __syncthreads();
    for (int off = 1; off < 1024; off <<= 1) {
        int t = (tid >= off) ? s[tid - off] : 0;
        __syncthreads();
        if (tid >= off) s[tid] += t;
        __syncthreads();
    }
    if (tid < nbkt) {
        int e = s[tid] - v;
        bptr[tid] = e;
        bcur[tid * 16] = e;
    }
}

// partition (blocks [0,GRID_P)) || gemm1 chunk B
__global__ __launch_bounds__(256) void k_part_gemm(
    const int* __restrict__ ei, int* __restrict__ bcur,
    unsigned* __restrict__ pairs, int E, int nbkt, int chunk,
    const float* __restrict__ x, const float* __restrict__ W1,
    __half* __restrict__ h1, int n, int gbase) {
    __shared__ int h[MAXBKT];
    __shared__ int cur[MAXBKT];
    if (blockIdx.x >= GRID_P) {
        gemm1_block(x, W1, h1, n, gbase + (int)blockIdx.x - GRID_P, threadIdx.x);
        return;
    }
    int tid = threadIdx.x;
    for (int i = tid; i < nbkt; i += blockDim.x) h[i] = 0;
    __syncthreads();
    int base = blockIdx.x * chunk;
    int end = min(base + chunk, E);
    for (int e = base + tid; e < end; e += blockDim.x)
        atomicAdd(&h[((unsigned)ei[E + e]) >> BSH], 1);
    __syncthreads();
    for (int i = tid; i < nbkt; i += blockDim.x) {
        int c = h[i];
        cur[i] = c ? atomicAdd(&bcur[i * 16], c) : 0;
    }
    __syncthreads();
    for (int e = base + tid; e < end; e += blockDim.x) {
        int d = ei[E + e];
        int b = ((unsigned)d) >> BSH;
        int pos = atomicAdd(&cur[b], 1);
        pairs[pos] = (((unsigned)ei[e]) << BSH) | (unsigned)(d & (NPB - 1));
    }
}

// bfill (blocks [0,nbkt)) || gemm1 chunk C
__global__ __launch_bounds__(NPB) void k_bfill_gemm(
    const unsigned* __restrict__ pairs, const int* __restrict__ bptr,
    int* __restrict__ row_ptr, int* __restrict__ srcarr,
    float* __restrict__ dinv, int n, int E, int nbkt,
    const float* __restrict__ x, const float* __restrict__ W1,
    __half* __restrict__ h1, int gbase) {
    __shared__ int h[NPB];
    __shared__ int s[NPB];
    int b = blockIdx.x, tid = threadIdx.x;
    if (b >= nbkt) {
        gemm1_block(x, W1, h1, n, gbase + b - nbkt, tid);
        return;
    }
    int pb = bptr[b];
    int pe = (b + 1 < nbkt) ? bptr[b + 1] : E;
    h[tid] = 0;
    __syncthreads();
    for (int p = pb + tid; p < pe; p += NPB)
        atomicAdd(&h[pairs[p] & (NPB - 1)], 1);
    __syncthreads();
    int cnt = h[tid];
    s[tid] = cnt;
    __syncthreads();
    for (int off = 1; off < NPB; off <<= 1) {
        int t = (tid >= off) ? s[tid - off] : 0;
        __syncthreads();
        if (tid >= off) s[tid] += t;
        __syncthreads();
    }
    int excl = s[tid] - cnt;
    int node = (b << BSH) + tid;
    if (node < n) {
        row_ptr[node] = pb + excl;
        dinv[node] = rsqrtf((float)(cnt + 1));  // +1 self loop
    }
    h[tid] = pb + excl;  // reuse as cursor
    __syncthreads();
    for (int p = pb + tid; p < pe; p += NPB) {
        unsigned v = pairs[p];
        int pos = atomicAdd(&h[v & (NPB - 1)], 1);
        srcarr[pos] = (int)(v >> BSH);
    }
    if (b == 0 && tid == 0) row_ptr[n] = E;
}

// ---------------- layer math ----------------

// h1 <- dinv[node] * h1 : factorizes norm = dinv[s]*dinv[d] out of the per-edge
// work. Gathers then just sum rows; dst-side dinv applied once per node.
__global__ __launch_bounds__(256) void k_scale(__half* __restrict__ h1,
                                               const float* __restrict__ dinv, int n) {
    int i = blockIdx.x * blockDim.x + threadIdx.x;
    if (i >= n) return;
    float d = dinv[i];
    float4* p = (float4*)(h1 + (size_t)i * HID);
    float4 a = p[0], b = p[1];
    __half2* ha = (__half2*)&a;
    __half2* hb = (__half2*)&b;
#pragma unroll
    for (int j = 0; j < 4; j++) {
        float2 f = __half22float2(ha[j]);
        ha[j] = __float22half2_rn(float2{f.x * d, f.y * d});
        f = __half22float2(hb[j]);
        hb[j] = __float22half2_rn(float2{f.x * d, f.y * d});
    }
    p[0] = a;
    p[1] = b;
}

__device__ __forceinline__ void add_row16(const __half* __restrict__ h1, int r,
                                          float* acc) {
    const float4* hr = (const float4*)(h1 + (size_t)r * HID);
    float4 raw0 = hr[0], raw1 = hr[1];
    const __half2* p0 = (const __half2*)&raw0;
    const __half2* p1 = (const __half2*)&raw1;
#pragma unroll
    for (int j = 0; j < 4; j++) {
        float2 f0 = __half22float2(p0[j]);
        float2 f1 = __half22float2(p1[j]);
        acc[2 * j + 0] += f0.x;
        acc[2 * j + 1] += f0.y;
        acc[8 + 2 * j + 0] += f1.x;
        acc[8 + 2 * j + 1] += f1.y;
    }
}

// Gather layer 1: 4 lanes/node; lane q takes edges eb+q, eb+q+4, ... with 4 edge
// rows in flight (pre-scaled rows -> no per-edge dinv load / multiply).
// Butterfly reduce, then fused self-loop + bias + relu + z@W2 -> fp16 t
// (pre-scaled by dinv[node]).
__global__ __launch_bounds__(256) void k_gather1(
    const int* __restrict__ row_ptr, const int* __restrict__ srcarr,
    const float* __restrict__ dinv, const __half* __restrict__ h1,
    const float* __restrict__ b1, const float* __restrict__ W2,
    __half* __restrict__ t, int n) {
    int g = blockIdx.x * blockDim.x + threadIdx.x;
    int node = g >> 2, q = g & 3;
    if (node >= n) return;
    int eb = row_ptr[node], ee = row_ptr[node + 1];
    float dc = dinv[node];
    float acc[HID];
#pragma unroll
    for (int j = 0; j < HID; j++) acc[j] = 0.f;
    int e = eb + q;
    for (; e + 12 < ee; e += 16) {
        int r0 = srcarr[e], r1 = srcarr[e + 4], r2 = srcarr[e + 8], r3 = srcarr[e + 12];
        add_row16(h1, r0, acc);
        add_row16(h1, r1, acc);
        add_row16(h1, r2, acc);
        add_row16(h1, r3, acc);
    }
    for (; e + 4 < ee; e += 8) {
        int r0 = srcarr[e], r1 = srcarr[e + 4];
        add_row16(h1, r0, acc);
        add_row16(h1, r1, acc);
    }
    if (e < ee) add_row16(h1, srcarr[e], acc);
#pragma unroll
    for (int m = 1; m < 4; m <<= 1)
#pragma unroll
        for (int j = 0; j < HID; j++) acc[j] += __shfl_xor(acc[j], m, 4);
    // self loop + bias + relu (redundant across the 4 lanes)
    float z[HID];
    {
        const float4* hs4 = (const float4*)(h1 + (size_t)node * HID);
        float4 raw0 = hs4[0], raw1 = hs4[1];
        const __half2* p0 = (const __half2*)&raw0;
        const __half2* p1 = (const __half2*)&raw1;
#pragma unroll
        for (int j = 0; j < 4; j++) {
            float2 f0 = __half22float2(p0[j]);
            float2 f1 = __half22float2(p1[j]);
            z[2 * j + 0] = fmaxf(fmaf(dc, acc[2 * j + 0] + f0.x, b1[2 * j + 0]), 0.f);
            z[2 * j + 1] = fmaxf(fmaf(dc, acc[2 * j + 1] + f0.y, b1[2 * j + 1]), 0.f);
            z[8 + 2 * j + 0] = fmaxf(fmaf(dc, acc[8 + 2 * j + 0] + f1.x, b1[8 + 2 * j + 0]), 0.f);
            z[8 + 2 * j + 1] = fmaxf(fmaf(dc, acc[8 + 2 * j + 1] + f1.y, b1[8 + 2 * j + 1]), 0.f);
        }
    }
    // lane q -> t columns 2q, 2q+1 (col 7 = pad = 0); pre-scale by dinv[node]
    int j0 = q * 2, j1 = q * 2 + 1;
    float t0 = 0.f, t1 = 0.f;
#pragma unroll
    for (int k = 0; k < HID; k++) {
        t0 = fmaf(z[k], W2[k * NCLS + j0], t0);
        if (j1 < NCLS) t1 = fmaf(z[k], W2[k * NCLS + j1], t1);
    }
    if (j1 >= NCLS) t1 = 0.f;
    t0 *= dc;
    t1 *= dc;
    ((__half2*)t)[(size_t)node * 4 + q] = __float22half2_rn(float2{t0, t1});
}

__device__ __forceinline__ void add_row8(const float4* __restrict__ t4, int r,
                                         float* acc) {
    float4 raw = t4[r];
    const __half2* p = (const __half2*)&raw;
#pragma unroll
    for (int j = 0; j < 4; j++) {
        float2 f = __half22float2(p[j]);
        acc[2 * j + 0] += f.x;
        acc[2 * j + 1] += f.y;
    }
}

// Gather layer 2: 8-half pre-scaled rows of t (one 16B load/edge), 4 edges in
// flight. Lane q writes out cols {2q, 2q+1} (col 7 skipped).
__global__ __launch_bounds__(256) void k_gather2(
    const int* __restrict__ row_ptr, const int* __restrict__ srcarr,
    const float* __restrict__ dinv, const __half* __restrict__ t,
    const float* __restrict__ b2, float* __restrict__ out, int n) {
    int g = blockIdx.x * blockDim.x + threadIdx.x;
    int node = g >> 2, q = g & 3;
    if (node >= n) return;
    int eb = row_ptr[node], ee = row_ptr[node + 1];
    float dc = dinv[node];
    float acc[8];
#pragma unroll
    for (int j = 0; j < 8; j++) acc[j] = 0.f;
    const float4* t4 = (const float4*)t;
    int e = eb + q;
    for (; e + 12 < ee; e += 16) {
        int r0 = srcarr[e], r1 = srcarr[e + 4], r2 = srcarr[e + 8], r3 = srcarr[e + 12];
        add_row8(t4, r0, acc);
        add_row8(t4, r1, acc);
        add_row8(t4, r2, acc);
        add_row8(t4, r3, acc);
    }
    for (; e + 4 < ee; e += 8) {
        int r0 = srcarr[e], r1 = srcarr[e + 4];
        add_row8(t4, r0, acc);
        add_row8(t4, r1, acc);
    }
    if (e < ee) add_row8(t4, srcarr[e], acc);
#pragma unroll
    for (int m = 1; m < 4; m <<= 1)
#pragma unroll
        for (int j = 0; j < 8; j++) acc[j] += __shfl_xor(acc[j], m, 4);
    float4 raws = t4[node];
    const __half2* ps = (const __half2*)&raws;
    float self[8];
#pragma unroll
    for (int j = 0; j < 4; j++) {
        float2 f = __half22float2(ps[j]);
        self[2 * j] = f.x;
        self[2 * j + 1] = f.y;
    }
    int j0 = q * 2, j1 = q * 2 + 1;
    float* o = out + (size_t)node * NCLS;
    o[j0] = fmaf(dc, acc[j0] + self[j0], b2[j0]);
    if (j1 < NCLS) o[j1] = fmaf(dc, acc[j1] + self[j1], b2[j1]);
}

extern "C" void kernel_launch(void* const* d_in, const int* in_sizes, int n_in,
                              void* d_out, int out_size, void* d_ws, size_t ws_size,
                              hipStream_t stream) {
    const float* x  = (const float*)d_in[0];
    const int*   ei = (const int*)d_in[1];
    const float* W1 = (const float*)d_in[2];
    const float* b1 = (const float*)d_in[3];
    const float* W2 = (const float*)d_in[4];
    const float* b2 = (const float*)d_in[5];
    float* out = (float*)d_out;

    int n = in_sizes[0] / F_IN;   // 100000
    int E = in_sizes[1] / 2;      // 3200000
    int nbkt = (n + NPB - 1) >> BSH;  // 391

    // workspace layout (h1 no longer aliases pairs: gemm overlaps the build)
    float* ws = (float*)d_ws;
    size_t off = 0;
    float* dinv    = ws + off;              off += (size_t)n;
    int*   row_ptr = (int*)(ws + off);      off += (size_t)n + 4;
    int*   srcarr  = (int*)(ws + off);      off += (size_t)E;
    unsigned* pairs = (unsigned*)(ws + off); off += (size_t)E;
    int*   bcnt    = (int*)(ws + off);      off += 1024 * 16;
    int*   bptr    = (int*)(ws + off);      off += 1024;
    int*   bcur    = (int*)(ws + off);      off += 1024 * 16;
    off = (off + 3) & ~(size_t)3;           // 16B align
    __half* h1     = (__half*)(ws + off);   off += 8 * (size_t)n;   // 16n halfs
    off = (off + 3) & ~(size_t)3;
    __half* t      = (__half*)(ws + off);                            // 8n halfs

    const int B = 256;
    int chunk = (E + GRID_P - 1) / GRID_P;

    // split gemm1's blocks across the three latency-bound build kernels
    int nb = (n + B - 1) / B;               // 391
    int nbA = nb < 64 ? nb : 64;
    int nbB = (nb - nbA) < 196 ? (nb - nbA) : 196;
    int nbC = nb - nbA - nbB;               // 131

    k_zero<<<dim3((1024 * 16 + B - 1) / B), dim3(B), 0, stream>>>(bcnt, 1024 * 16);
    k_bhist_gemm<<<dim3(GRID_P + nbA), dim3(B), 0, stream>>>(ei + E, bcnt, E, nbkt, chunk,
                                                             x, W1, h1, n);
    k_bscan<<<dim3(1), dim3(1024), 0, stream>>>(bcnt, bptr, bcur, nbkt);
    k_part_gemm<<<dim3(GRID_P + nbB), dim3(B), 0, stream>>>(ei, bcur, pairs, E, nbkt, chunk,
                                                            x, W1, h1, n, nbA);
    k_bfill_gemm<<<dim3(nbkt + nbC), dim3(NPB), 0, stream>>>(pairs, bptr, row_ptr, srcarr,
                                                             dinv, n, E, nbkt,
                                                             x, W1, h1, nbA + nbB);
    k_scale<<<dim3(nb), dim3(B), 0, stream>>>(h1, dinv, n);
    k_gather1<<<dim3((n * 4 + B - 1) / B), dim3(B), 0, stream>>>(row_ptr, srcarr, dinv, h1, b1, W2, t, n);
    k_gather2<<<dim3((n * 4 + B - 1) / B), dim3(B), 0, stream>>>(row_ptr, srcarr, dinv, t, b2, out, n);
}

// Round 4
// 486.030 us; speedup vs baseline: 1.0781x; 1.0152x over previous
//
#include <hip/hip_runtime.h>
#include <hip/hip_fp16.h>

#define F_IN 512
#define HID  16
#define NCLS 7
#define BSH  8            // log2(nodes per bucket)
#define NPB  256          // nodes per bucket
#define MAXBKT 1024       // supports n <= 262144
#define GRID_P 512        // blocks for hist/partition passes

// ---------------- GEMM1 body (used by fused kernels) ----------------
// h1 = fp32(x @ W1) stored fp16, 32B rows (3.2MB -> per-XCD-L2-resident for gathers).
__device__ __forceinline__ void gemm1_block(const float* __restrict__ x,
                                            const float* __restrict__ W1,
                                            __half* __restrict__ h1, int n,
                                            int vblk, int tid) {
    int node = vblk * 256 + tid;
    if (node >= n) return;
    float acc[HID];
#pragma unroll
    for (int j = 0; j < HID; j++) acc[j] = 0.f;
    const float* xr = x + (size_t)node * F_IN;
    for (int k0 = 0; k0 < F_IN; k0 += 32) {
        float4 xv[8];
        const float4* xp = (const float4*)(xr + k0);
#pragma unroll
        for (int u = 0; u < 8; u++) xv[u] = xp[u];
#pragma unroll
        for (int u = 0; u < 8; u++) {
#pragma unroll
            for (int kk = 0; kk < 4; kk++) {
                float xk = ((const float*)&xv[u])[kk];
                const float* wr = W1 + (size_t)(k0 + u * 4 + kk) * HID;
#pragma unroll
                for (int j = 0; j < HID; j++) acc[j] = fmaf(xk, wr[j], acc[j]);
            }
        }
    }
    __half2 hp[8];
#pragma unroll
    for (int j = 0; j < 8; j++)
        hp[j] = __float22half2_rn(float2{acc[2 * j], acc[2 * j + 1]});
    float4* o4 = (float4*)(h1 + (size_t)node * HID);
    o4[0] = *(float4*)&hp[0];
    o4[1] = *(float4*)&hp[4];
}

// ---------------- bucketed CSR build ----------------

__global__ void k_zero(int* __restrict__ p, int m) {
    int i = blockIdx.x * blockDim.x + threadIdx.x;
    if (i < m) p[i] = 0;
}

// bhist (blocks [0,GRID_P)) || gemm1 chunk A (blocks >= GRID_P)
__global__ __launch_bounds__(256) void k_bhist_gemm(
    const int* __restrict__ dst, int* __restrict__ bcnt, int E, int nbkt, int chunk,
    const float* __restrict__ x, const float* __restrict__ W1,
    __half* __restrict__ h1, int n) {
    __shared__ int h[MAXBKT];
    if (blockIdx.x >= GRID_P) {
        gemm1_block(x, W1, h1, n, (int)blockIdx.x - GRID_P, threadIdx.x);
        return;
    }
    for (int i = threadIdx.x; i < nbkt; i += blockDim.x) h[i] = 0;
    __syncthreads();
    int base = blockIdx.x * chunk;
    int end = min(base + chunk, E);
    int end4 = base + ((end - base) & ~3);   // int4 region; scalar tail after
    for (int e = base + 4 * (int)threadIdx.x; e < end4; e += 4 * (int)blockDim.x) {
        int4 d4 = *(const int4*)(dst + e);
        atomicAdd(&h[((unsigned)d4.x) >> BSH], 1);
        atomicAdd(&h[((unsigned)d4.y) >> BSH], 1);
        atomicAdd(&h[((unsigned)d4.z) >> BSH], 1);
        atomicAdd(&h[((unsigned)d4.w) >> BSH], 1);
    }
    for (int e = end4 + (int)threadIdx.x; e < end; e += (int)blockDim.x)
        atomicAdd(&h[((unsigned)dst[e]) >> BSH], 1);
    __syncthreads();
    for (int i = threadIdx.x; i < nbkt; i += blockDim.x)
        if (h[i]) atomicAdd(&bcnt[i * 16], h[i]);   // stride-16: one counter per line
}

__global__ void k_bscan(const int* __restrict__ bcnt, int* __restrict__ bptr,
                        int* __restrict__ bcur, int nbkt) {
    __shared__ int s[1024];
    int tid = threadIdx.x;
    int v = (tid < nbkt) ? bcnt[tid * 16] : 0;
    s[tid] = v;
    __syncthreads();
    for (int off = 1; off < 1024; off <<= 1) {
        int t = (tid >= off) ? s[tid - off] : 0;
        __syncthreads();
        if (tid >= off) s[tid] += t;
        __syncthreads();
    }
    if (tid < nbkt) {
        int e = s[tid] - v;
        bptr[tid] = e;
        bcur[tid * 16] = e;
    }
}

// partition (blocks [0,GRID_P)) || gemm1 chunk B
__global__ __launch_bounds__(256) void k_part_gemm(
    const int* __restrict__ ei, int* __restrict__ bcur,
    unsigned* __restrict__ pairs, int E, int nbkt, int chunk,
    const float* __restrict__ x, const float* __restrict__ W1,
    __half* __restrict__ h1, int n, int gbase) {
    __shared__ int h[MAXBKT];
    __shared__ int cur[MAXBKT];
    if (blockIdx.x >= GRID_P) {
        gemm1_block(x, W1, h1, n, gbase + (int)blockIdx.x - GRID_P, threadIdx.x);
        return;
    }
    int tid = threadIdx.x;
    for (int i = tid; i < nbkt; i += blockDim.x) h[i] = 0;
    __syncthreads();
    int base = blockIdx.x * chunk;
    int end = min(base + chunk, E);
    int end4 = base + ((end - base) & ~3);
    for (int e = base + 4 * tid; e < end4; e += 4 * (int)blockDim.x) {
        int4 d4 = *(const int4*)(ei + E + e);
        atomicAdd(&h[((unsigned)d4.x) >> BSH], 1);
        atomicAdd(&h[((unsigned)d4.y) >> BSH], 1);
        atomicAdd(&h[((unsigned)d4.z) >> BSH], 1);
        atomicAdd(&h[((unsigned)d4.w) >> BSH], 1);
    }
    for (int e = end4 + tid; e < end; e += (int)blockDim.x)
        atomicAdd(&h[((unsigned)ei[E + e]) >> BSH], 1);
    __syncthreads();
    for (int i = tid; i < nbkt; i += blockDim.x) {
        int c = h[i];
        cur[i] = c ? atomicAdd(&bcur[i * 16], c) : 0;
    }
    __syncthreads();
    for (int e = base + 4 * tid; e < end4; e += 4 * (int)blockDim.x) {
        int4 s4 = *(const int4*)(ei + e);
        int4 d4 = *(const int4*)(ei + E + e);
#pragma unroll
        for (int k = 0; k < 4; k++) {
            int sk = (&s4.x)[k];
            int dk = (&d4.x)[k];
            int b = ((unsigned)dk) >> BSH;
            int pos = atomicAdd(&cur[b], 1);
            pairs[pos] = (((unsigned)sk) << BSH) | (unsigned)(dk & (NPB - 1));
        }
    }
    for (int e = end4 + tid; e < end; e += (int)blockDim.x) {
        int d = ei[E + e];
        int b = ((unsigned)d) >> BSH;
        int pos = atomicAdd(&cur[b], 1);
        pairs[pos] = (((unsigned)ei[e]) << BSH) | (unsigned)(d & (NPB - 1));
    }
}

// bfill (blocks [0,nbkt)) || gemm1 chunk C
__global__ __launch_bounds__(NPB) void k_bfill_gemm(
    const unsigned* __restrict__ pairs, const int* __restrict__ bptr,
    int* __restrict__ row_ptr, int* __restrict__ srcarr,
    float* __restrict__ dinv, int n, int E, int nbkt,
    const float* __restrict__ x, const float* __restrict__ W1,
    __half* __restrict__ h1, int gbase) {
    __shared__ int h[NPB];
    __shared__ int s[NPB];
    int b = blockIdx.x, tid = threadIdx.x;
    if (b >= nbkt) {
        gemm1_block(x, W1, h1, n, gbase + b - nbkt, tid);
        return;
    }
    int pb = bptr[b];
    int pe = (b + 1 < nbkt) ? bptr[b + 1] : E;
    h[tid] = 0;
    __syncthreads();
    for (int p = pb + tid; p < pe; p += NPB)
        atomicAdd(&h[pairs[p] & (NPB - 1)], 1);
    __syncthreads();
    int cnt = h[tid];
    s[tid] = cnt;
    __syncthreads();
    for (int off = 1; off < NPB; off <<= 1) {
        int t = (tid >= off) ? s[tid - off] : 0;
        __syncthreads();
        if (tid >= off) s[tid] += t;
        __syncthreads();
    }
    int excl = s[tid] - cnt;
    int node = (b << BSH) + tid;
    if (node < n) {
        row_ptr[node] = pb + excl;
        dinv[node] = rsqrtf((float)(cnt + 1));  // +1 self loop
    }
    h[tid] = pb + excl;  // reuse as cursor
    __syncthreads();
    for (int p = pb + tid; p < pe; p += NPB) {
        unsigned v = pairs[p];
        int pos = atomicAdd(&h[v & (NPB - 1)], 1);
        srcarr[pos] = (int)(v >> BSH);
    }
    if (b == 0 && tid == 0) row_ptr[n] = E;
}

// ---------------- layer math ----------------

// h1 <- dinv[node] * h1 : factorizes norm = dinv[s]*dinv[d] out of the per-edge
// work. Gathers then just sum rows; dst-side dinv applied once per node.
__global__ __launch_bounds__(256) void k_scale(__half* __restrict__ h1,
                                               const float* __restrict__ dinv, int n) {
    int i = blockIdx.x * blockDim.x + threadIdx.x;
    if (i >= n) return;
    float d = dinv[i];
    float4* p = (float4*)(h1 + (size_t)i * HID);
    float4 a = p[0], b = p[1];
    __half2* ha = (__half2*)&a;
    __half2* hb = (__half2*)&b;
#pragma unroll
    for (int j = 0; j < 4; j++) {
        float2 f = __half22float2(ha[j]);
        ha[j] = __float22half2_rn(float2{f.x * d, f.y * d});
        f = __half22float2(hb[j]);
        hb[j] = __float22half2_rn(float2{f.x * d, f.y * d});
    }
    p[0] = a;
    p[1] = b;
}

__device__ __forceinline__ void add_row16(const __half* __restrict__ h1, int r,
                                          float* acc) {
    const float4* hr = (const float4*)(h1 + (size_t)r * HID);
    float4 raw0 = hr[0], raw1 = hr[1];
    const __half2* p0 = (const __half2*)&raw0;
    const __half2* p1 = (const __half2*)&raw1;
#pragma unroll
    for (int j = 0; j < 4; j++) {
        float2 f0 = __half22float2(p0[j]);
        float2 f1 = __half22float2(p1[j]);
        acc[2 * j + 0] += f0.x;
        acc[2 * j + 1] += f0.y;
        acc[8 + 2 * j + 0] += f1.x;
        acc[8 + 2 * j + 1] += f1.y;
    }
}

// Gather layer 1: 4 lanes/node; lane q takes edges eb+q, eb+q+4, ... with 4 edge
// rows in flight (pre-scaled rows -> no per-edge dinv load / multiply).
// Butterfly reduce, then fused self-loop + bias + relu + z@W2 -> fp16 t
// (pre-scaled by dinv[node]).
__global__ __launch_bounds__(256) void k_gather1(
    const int* __restrict__ row_ptr, const int* __restrict__ srcarr,
    const float* __restrict__ dinv, const __half* __restrict__ h1,
    const float* __restrict__ b1, const float* __restrict__ W2,
    __half* __restrict__ t, int n) {
    int g = blockIdx.x * blockDim.x + threadIdx.x;
    int node = g >> 2, q = g & 3;
    if (node >= n) return;
    int eb = row_ptr[node], ee = row_ptr[node + 1];
    float dc = dinv[node];
    float acc[HID];
#pragma unroll
    for (int j = 0; j < HID; j++) acc[j] = 0.f;
    int e = eb + q;
    for (; e + 12 < ee; e += 16) {
        int r0 = srcarr[e], r1 = srcarr[e + 4], r2 = srcarr[e + 8], r3 = srcarr[e + 12];
        add_row16(h1, r0, acc);
        add_row16(h1, r1, acc);
        add_row16(h1, r2, acc);
        add_row16(h1, r3, acc);
    }
    for (; e + 4 < ee; e += 8) {
        int r0 = srcarr[e], r1 = srcarr[e + 4];
        add_row16(h1, r0, acc);
        add_row16(h1, r1, acc);
    }
    if (e < ee) add_row16(h1, srcarr[e], acc);
#pragma unroll
    for (int m = 1; m < 4; m <<= 1)
#pragma unroll
        for (int j = 0; j < HID; j++) acc[j] += __shfl_xor(acc[j], m, 4);
    // self loop + bias + relu (redundant across the 4 lanes)
    float z[HID];
    {
        const float4* hs4 = (const float4*)(h1 + (size_t)node * HID);
        float4 raw0 = hs4[0], raw1 = hs4[1];
        const __half2* p0 = (const __half2*)&raw0;
        const __half2* p1 = (const __half2*)&raw1;
#pragma unroll
        for (int j = 0; j < 4; j++) {
            float2 f0 = __half22float2(p0[j]);
            float2 f1 = __half22float2(p1[j]);
            z[2 * j + 0] = fmaxf(fmaf(dc, acc[2 * j + 0] + f0.x, b1[2 * j + 0]), 0.f);
            z[2 * j + 1] = fmaxf(fmaf(dc, acc[2 * j + 1] + f0.y, b1[2 * j + 1]), 0.f);
            z[8 + 2 * j + 0] = fmaxf(fmaf(dc, acc[8 + 2 * j + 0] + f1.x, b1[8 + 2 * j + 0]), 0.f);
            z[8 + 2 * j + 1] = fmaxf(fmaf(dc, acc[8 + 2 * j + 1] + f1.y, b1[8 + 2 * j + 1]), 0.f);
        }
    }
    // lane q -> t columns 2q, 2q+1 (col 7 = pad = 0); pre-scale by dinv[node]
    int j0 = q * 2, j1 = q * 2 + 1;
    float t0 = 0.f, t1 = 0.f;
#pragma unroll
    for (int k = 0; k < HID; k++) {
        t0 = fmaf(z[k], W2[k * NCLS + j0], t0);
        if (j1 < NCLS) t1 = fmaf(z[k], W2[k * NCLS + j1], t1);
    }
    if (j1 >= NCLS) t1 = 0.f;
    t0 *= dc;
    t1 *= dc;
    ((__half2*)t)[(size_t)node * 4 + q] = __float22half2_rn(float2{t0, t1});
}

__device__ __forceinline__ void add_row8(const float4* __restrict__ t4, int r,
                                         float* acc) {
    float4 raw = t4[r];
    const __half2* p = (const __half2*)&raw;
#pragma unroll
    for (int j = 0; j < 4; j++) {
        float2 f = __half22float2(p[j]);
        acc[2 * j + 0] += f.x;
        acc[2 * j + 1] += f.y;
    }
}

// Gather layer 2: 8-half pre-scaled rows of t (one 16B load/edge), 4 edges in
// flight. Lane q writes out cols {2q, 2q+1} (col 7 skipped).
__global__ __launch_bounds__(256) void k_gather2(
    const int* __restrict__ row_ptr, const int* __restrict__ srcarr,
    const float* __restrict__ dinv, const __half* __restrict__ t,
    const float* __restrict__ b2, float* __restrict__ out, int n) {
    int g = blockIdx.x * blockDim.x + threadIdx.x;
    int node = g >> 2, q = g & 3;
    if (node >= n) return;
    int eb = row_ptr[node], ee = row_ptr[node + 1];
    float dc = dinv[node];
    float acc[8];
#pragma unroll
    for (int j = 0; j < 8; j++) acc[j] = 0.f;
    const float4* t4 = (const float4*)t;
    int e = eb + q;
    for (; e + 12 < ee; e += 16) {
        int r0 = srcarr[e], r1 = srcarr[e + 4], r2 = srcarr[e + 8], r3 = srcarr[e + 12];
        add_row8(t4, r0, acc);
        add_row8(t4, r1, acc);
        add_row8(t4, r2, acc);
        add_row8(t4, r3, acc);
    }
    for (; e + 4 < ee; e += 8) {
        int r0 = srcarr[e], r1 = srcarr[e + 4];
        add_row8(t4, r0, acc);
        add_row8(t4, r1, acc);
    }
    if (e < ee) add_row8(t4, srcarr[e], acc);
#pragma unroll
    for (int m = 1; m < 4; m <<= 1)
#pragma unroll
        for (int j = 0; j < 8; j++) acc[j] += __shfl_xor(acc[j], m, 4);
    float4 raws = t4[node];
    const __half2* ps = (const __half2*)&raws;
    float self[8];
#pragma unroll
    for (int j = 0; j < 4; j++) {
        float2 f = __half22float2(ps[j]);
        self[2 * j] = f.x;
        self[2 * j + 1] = f.y;
    }
    int j0 = q * 2, j1 = q * 2 + 1;
    float* o = out + (size_t)node * NCLS;
    o[j0] = fmaf(dc, acc[j0] + self[j0], b2[j0]);
    if (j1 < NCLS) o[j1] = fmaf(dc, acc[j1] + self[j1], b2[j1]);
}

extern "C" void kernel_launch(void* const* d_in, const int* in_sizes, int n_in,
                              void* d_out, int out_size, void* d_ws, size_t ws_size,
                              hipStream_t stream) {
    const float* x  = (const float*)d_in[0];
    const int*   ei = (const int*)d_in[1];
    const float* W1 = (const float*)d_in[2];
    const float* b1 = (const float*)d_in[3];
    const float* W2 = (const float*)d_in[4];
    const float* b2 = (const float*)d_in[5];
    float* out = (float*)d_out;

    int n = in_sizes[0] / F_IN;   // 100000
    int E = in_sizes[1] / 2;      // 3200000
    int nbkt = (n + NPB - 1) >> BSH;  // 391

    // workspace layout (h1 no longer aliases pairs: gemm overlaps the build)
    float* ws = (float*)d_ws;
    size_t off = 0;
    float* dinv    = ws + off;              off += (size_t)n;
    int*   row_ptr = (int*)(ws + off);      off += (size_t)n + 4;
    int*   srcarr  = (int*)(ws + off);      off += (size_t)E;
    unsigned* pairs = (unsigned*)(ws + off); off += (size_t)E;
    int*   bcnt    = (int*)(ws + off);      off += 1024 * 16;
    int*   bptr    = (int*)(ws + off);      off += 1024;
    int*   bcur    = (int*)(ws + off);      off += 1024 * 16;
    off = (off + 3) & ~(size_t)3;           // 16B align
    __half* h1     = (__half*)(ws + off);   off += 8 * (size_t)n;   // 16n halfs
    off = (off + 3) & ~(size_t)3;
    __half* t      = (__half*)(ws + off);                            // 8n halfs

    const int B = 256;
    int chunk = (((E + GRID_P - 1) / GRID_P) + 3) & ~3;   // multiple of 4

    // split gemm1's blocks across the three latency-bound build kernels
    int nb = (n + B - 1) / B;               // 391
    int nbA = nb < 64 ? nb : 64;
    int nbB = (nb - nbA) < 196 ? (nb - nbA) : 196;
    int nbC = nb - nbA - nbB;               // 131

    k_zero<<<dim3((1024 * 16 + B - 1) / B), dim3(B), 0, stream>>>(bcnt, 1024 * 16);
    k_bhist_gemm<<<dim3(GRID_P + nbA), dim3(B), 0, stream>>>(ei + E, bcnt, E, nbkt, chunk,
                                                             x, W1, h1, n);
    k_bscan<<<dim3(1), dim3(1024), 0, stream>>>(bcnt, bptr, bcur, nbkt);
    k_part_gemm<<<dim3(GRID_P + nbB), dim3(B), 0, stream>>>(ei, bcur, pairs, E, nbkt, chunk,
                                                            x, W1, h1, n, nbA);
    k_bfill_gemm<<<dim3(nbkt + nbC), dim3(NPB), 0, stream>>>(pairs, bptr, row_ptr, srcarr,
                                                             dinv, n, E, nbkt,
                                                             x, W1, h1, nbA + nbB);
    k_scale<<<dim3((n + B - 1) / B), dim3(B), 0, stream>>>(h1, dinv, n);
    k_gather1<<<dim3((n * 4 + B - 1) / B), dim3(B), 0, stream>>>(row_ptr, srcarr, dinv, h1, b1, W2, t, n);
    k_gather2<<<dim3((n * 4 + B - 1) / B), dim3(B), 0, stream>>>(row_ptr, srcarr, dinv, t, b2, out, n);
}